// Round 6
// baseline (3690.845 us; speedup 1.0000x reference)
//
#include <hip/hip_runtime.h>
#include <math.h>

#define NN 50000
#define NE 600000
#define ECAP 230000  // capacity for filtered edges (actual ~175K)
#define DD 128
#define D3 384
#define NB_ 20
#define HH 64
#define NG_ 512
#define LSZ 180224   // shorts per layer of transposed-bf16 weights

typedef short v8s __attribute__((ext_vector_type(8)));
typedef short v4sh __attribute__((ext_vector_type(4)));
typedef float v4f __attribute__((ext_vector_type(4)));

__device__ __forceinline__ float silu_f(float z) { return z / (1.0f + expf(-z)); }

__device__ __forceinline__ short f2bf(float f) {
  unsigned u = __float_as_uint(f);
  u += 0x7FFF + ((u >> 16) & 1);          // RNE
  return (short)(u >> 16);
}
__device__ __forceinline__ float bf2f(short s) {
  return __uint_as_float(((unsigned)(unsigned short)s) << 16);
}
__device__ __forceinline__ void split2(float x, short& h, short& l) {
  h = f2bf(x);
  l = f2bf(x - bf2f(h));
}
// split a float4 and store hi/lo as short4 (8B LDS stores)
__device__ __forceinline__ void split_store4(float4 f, short* hp, short* lp) {
  short h0,l0,h1,l1,h2,l2,h3,l3;
  split2(f.x,h0,l0); split2(f.y,h1,l1); split2(f.z,h2,l2); split2(f.w,h3,l3);
  v4sh hv = {h0,h1,h2,h3}, lv = {l0,l1,l2,l3};
  *(v4sh*)hp = hv; *(v4sh*)lp = lv;
}
// 3-term Markidis split: acc += ah@bh + al@bh + ah@bl   (proven: absmax 4.3e9)
#define MFMA3(acc, ah, al, bh, bl) \
  acc = __builtin_amdgcn_mfma_f32_16x16x32_bf16(ah, bh, acc, 0, 0, 0); \
  acc = __builtin_amdgcn_mfma_f32_16x16x32_bf16(al, bh, acc, 0, 0, 0); \
  acc = __builtin_amdgcn_mfma_f32_16x16x32_bf16(ah, bl, acc, 0, 0, 0);

// ---------------- utility ----------------
__global__ void zero_f_kernel(float* __restrict__ p, long n) {
  long i = (long)blockIdx.x * blockDim.x + threadIdx.x;
  long s = (long)gridDim.x * blockDim.x;
  for (; i < n; i += s) p[i] = 0.0f;
}

__global__ void zero_i_kernel(int* __restrict__ p, long n) {
  long i = (long)blockIdx.x * blockDim.x + threadIdx.x;
  long s = (long)gridDim.x * blockDim.x;
  for (; i < n; i += s) p[i] = 0;
}

__global__ void init_x_kernel(const int* __restrict__ at_no, const float* __restrict__ emb,
                              float* __restrict__ x) {
  int i = blockIdx.x * blockDim.x + threadIdx.x;
  if (i >= NN * DD) return;
  x[i] = emb[at_no[i >> 7] * DD + (i & 127)];
}

// ---------------- weight prep: fp32 [K][N] -> transposed bf16 hi/lo [N][K] ----------------
__global__ void prep_w_kernel(const float* __restrict__ Wm1, const float* __restrict__ Wm2,
                              const float* __restrict__ U, const float* __restrict__ V,
                              const float* __restrict__ Wu1, const float* __restrict__ Wu2,
                              short* __restrict__ hi, short* __restrict__ lo) {
  int idx = blockIdx.x * 256 + threadIdx.x;
  if (idx >= 3 * LSZ) return;
  int l = idx / LSZ, r = idx % LSZ;
  const float* src; int K, N, nk;
  if (r < 16384)       { src = Wm1 + (size_t)l*16384; K = 128; N = 128; nk = r; }
  else if (r < 65536)  { src = Wm2 + (size_t)l*49152; K = 128; N = 384; nk = r - 16384; }
  else if (r < 81920)  { src = U   + (size_t)l*16384; K = 128; N = 128; nk = r - 65536; }
  else if (r < 98304)  { src = V   + (size_t)l*16384; K = 128; N = 128; nk = r - 81920; }
  else if (r < 131072) { src = Wu1 + (size_t)l*32768; K = 256; N = 128; nk = r - 98304; }
  else                 { src = Wu2 + (size_t)l*49152; K = 128; N = 384; nk = r - 131072; }
  int n = nk / K, k = nk - n * K;
  float xx = src[(size_t)k * N + n];
  short h = f2bf(xx);
  hi[idx] = h;
  lo[idx] = f2bf(xx - bf2f(h));
}

// Wf transpose: [NB_][D3] fp32 -> wfT[128][64] per layer (c = ch*20+k, padded to 64)
// so each d-lane's 60 filter weights are one contiguous 240B region (15 x float4 loads).
__global__ void prep_wf_kernel(const float* __restrict__ Wf, float* __restrict__ wfT) {
  int idx = blockIdx.x * 256 + threadIdx.x;
  if (idx >= 3 * 8192) return;
  int l = idx / 8192, r = idx % 8192;
  int d = r >> 6, c = r & 63;
  float v = 0.0f;
  if (c < 60) {
    int ch = c / 20, k = c % 20;
    v = Wf[(size_t)l * NB_ * D3 + (size_t)k * D3 + ch * DD + d];
  }
  wfT[(size_t)l * 8192 + d * 64 + c] = v;
}

// ---------------- CSR build (dst-sorted), filtering dist>=CUTOFF edges ----------------
__global__ void hist_kernel(const int* __restrict__ ei, const float* __restrict__ pos,
                            int* __restrict__ counts) {
  int e = blockIdx.x * blockDim.x + threadIdx.x;
  if (e >= NE) return;
  int s = ei[e], d = ei[NE + e];
  float dx = pos[3*d]   - pos[3*s];
  float dy = pos[3*d+1] - pos[3*s+1];
  float dz = pos[3*d+2] - pos[3*s+2];
  float d2 = dx*dx + dy*dy + dz*dz + 1e-12f;
  if (d2 < 25.0f) atomicAdd(&counts[d], 1);
}

__global__ void scan_kernel(const int* __restrict__ counts, int* __restrict__ indptr, int n) {
  __shared__ int sm[1024];
  __shared__ int carry_s;
  if (threadIdx.x == 0) carry_s = 0;
  __syncthreads();
  for (int start = 0; start < n; start += 1024) {
    int i = start + (int)threadIdx.x;
    int val = (i < n) ? counts[i] : 0;
    sm[threadIdx.x] = val;
    __syncthreads();
    for (int off = 1; off < 1024; off <<= 1) {
      int t = (threadIdx.x >= (unsigned)off) ? sm[threadIdx.x - off] : 0;
      __syncthreads();
      sm[threadIdx.x] += t;
      __syncthreads();
    }
    int c = carry_s;
    if (i < n) indptr[i] = c + sm[threadIdx.x] - val;
    __syncthreads();
    if (threadIdx.x == 0) carry_s = c + sm[1023];
    __syncthreads();
  }
  if (threadIdx.x == 0) indptr[n] = carry_s;
}

__global__ void fill_kernel(const int* __restrict__ ei, const float* __restrict__ pos,
                            const int* __restrict__ indptr, int* __restrict__ cursor,
                            int* __restrict__ srcs, float4* __restrict__ eg1,
                            float4* __restrict__ eg2) {
  int e = blockIdx.x * blockDim.x + threadIdx.x;
  if (e >= NE) return;
  int s = ei[e], d = ei[NE + e];
  float dx = pos[3*d]   - pos[3*s];
  float dy = pos[3*d+1] - pos[3*s+1];
  float dz = pos[3*d+2] - pos[3*s+2];
  float d2 = dx*dx + dy*dy + dz*dz + 1e-12f;
  if (d2 < 25.0f) {
    int p = atomicAdd(&cursor[d], 1);
    int slot = indptr[d] + p;
    float dist = sqrtf(d2);
    float inv = 1.0f / dist;
    float wang = 0.62831853071795864769f * dist;   // pi*dist/CUTOFF
    float s1 = __sinf(wang), c1 = __cosf(wang);
    float fc = 0.5f * (c1 + 1.0f);
    srcs[slot] = s;
    eg1[slot] = make_float4(s1, c1, fc, fc * inv);
    eg2[slot] = make_float4(dx * inv, dy * inv, dz * inv, 0.0f);
  }
}

// ---------------- fused node MLP: phi = silu(x@Wm1+b1)@Wm2+b2, tri-slice out ----------------
// Row-local chain; t2 never leaves LDS. 512 thr / 8 waves, 32 rows/block.
__global__ void __launch_bounds__(512) mlp_phi_kernel(
    const float* __restrict__ x,
    const short* __restrict__ W1h, const short* __restrict__ W1l, const float* __restrict__ b1,
    const short* __restrict__ W2h, const short* __restrict__ W2l, const float* __restrict__ b2,
    float* __restrict__ C0, float* __restrict__ C1, float* __restrict__ C2, int M) {
  __shared__ short sm[4 * 32 * 136];   // XH | XL | TH | TL
  #define XH_(r,c) sm[(r)*136 + (c)]
  #define XL_(r,c) sm[4352 + (r)*136 + (c)]
  #define TH_(r,c) sm[8704 + (r)*136 + (c)]
  #define TL_(r,c) sm[13056 + (r)*136 + (c)]
  int tid = threadIdx.x;
  long r0 = (long)blockIdx.x * 32;
  #pragma unroll
  for (int i = 0; i < 2; i++) {
    int lin = i*512 + tid;
    int r = lin >> 5, c4 = lin & 31;
    long row = r0 + r; if (row >= M) row = M - 1;
    float4 f = *(const float4*)(x + row*128 + c4*4);
    split_store4(f, &XH_(r, c4*4), &XL_(r, c4*4));
  }
  __syncthreads();
  int lane = tid & 63, wv = tid >> 6;   // wv 0..7
  int l15 = lane & 15, q = lane >> 4;
  // GEMM1: t2 = silu(x@Wm1 + b1); wave w owns cols w*16+l15
  {
    int n = wv*16 + l15;
    v4f acc[2] = {};
    #pragma unroll
    for (int s = 0; s < 4; s++) {
      v8s bh = *(const v8s*)(W1h + (long)n*128 + s*32 + q*8);
      v8s bl = *(const v8s*)(W1l + (long)n*128 + s*32 + q*8);
      #pragma unroll
      for (int mt = 0; mt < 2; mt++) {
        v8s ah = *(const v8s*)&XH_(mt*16 + l15, s*32 + q*8);
        v8s al = *(const v8s*)&XL_(mt*16 + l15, s*32 + q*8);
        MFMA3(acc[mt], ah, al, bh, bl);
      }
    }
    float bb = b1[n];
    #pragma unroll
    for (int mt = 0; mt < 2; mt++)
      #pragma unroll
      for (int i = 0; i < 4; i++) {
        short h, l;
        split2(silu_f(acc[mt][i] + bb), h, l);
        TH_(mt*16 + q*4 + i, n) = h;
        TL_(mt*16 + q*4 + i, n) = l;
      }
  }
  __syncthreads();
  // GEMM2: phi = t2@Wm2 + b2 (384 cols; wave w -> n-tiles w*3..w*3+2)
  v4f acc[2][3] = {};
  #pragma unroll
  for (int s = 0; s < 4; s++) {
    v8s ah[2], al[2];
    #pragma unroll
    for (int mt = 0; mt < 2; mt++) {
      ah[mt] = *(const v8s*)&TH_(mt*16 + l15, s*32 + q*8);
      al[mt] = *(const v8s*)&TL_(mt*16 + l15, s*32 + q*8);
    }
    #pragma unroll
    for (int j = 0; j < 3; j++) {
      int n = (wv*3 + j)*16 + l15;
      v8s bh = *(const v8s*)(W2h + (long)n*128 + s*32 + q*8);
      v8s bl = *(const v8s*)(W2l + (long)n*128 + s*32 + q*8);
      #pragma unroll
      for (int mt = 0; mt < 2; mt++) { MFMA3(acc[mt][j], ah[mt], al[mt], bh, bl); }
    }
  }
  #pragma unroll
  for (int j = 0; j < 3; j++) {
    int n = (wv*3 + j)*16 + l15;
    int sl = n >> 7, col = n & 127;
    float* C = (sl == 0) ? C0 : (sl == 1) ? C1 : C2;
    float bb = b2[n];
    #pragma unroll
    for (int mt = 0; mt < 2; mt++)
      #pragma unroll
      for (int i = 0; i < 4; i++) {
        long row = r0 + mt*16 + q*4 + i;
        if (row < M) C[row*128 + col] = acc[mt][j][i] + bb;
      }
  }
  #undef XH_
  #undef XL_
  #undef TH_
  #undef TL_
}

// ---------------- R20: dedicated edge-sweep kernel (max-TLP gather engine) ----------------
// One node per 128-thread block, ZERO LDS, small VGPR footprint -> up to 32 waves/CU
// (2.5x the gather concurrency muva could reach at its 35.8KB LDS / ~13 waves/CU).
// Adds x-delta IN PLACE (x not read by this kernel; mlp_phi already done) and writes
// v-deltas to vd. Depth-2 zero-move pipeline identical to R17's proven sweep body.
__global__ void __launch_bounds__(128, 8) sweep_kernel(
    const float* __restrict__ phi0, const float* __restrict__ phi1,
    const float* __restrict__ phi2, const float* __restrict__ vA,
    float* __restrict__ x, float* __restrict__ vd,
    const int* __restrict__ srcs, const float4* __restrict__ eg1,
    const float4* __restrict__ eg2, const int* __restrict__ indptr,
    const float* __restrict__ wfT_l, const float* __restrict__ bf_l) {
  const long NND = (long)NN*DD;
  int n = blockIdx.x;
  int d = threadIdx.x;
  // per-lane filter weights: 15 x float4 from contiguous 240B (L1-resident wfT row;
  // compiler may remat these per edge — acceptable, short L1-hit queue)
  v4f wfv[15];
  {
    const float* wrow = wfT_l + d*64;
    #pragma unroll
    for (int j = 0; j < 15; j++) wfv[j] = *(const v4f*)(wrow + j*4);
  }
  #define WF0(k) wfv[(k)>>2][(k)&3]
  #define WF1(k) wfv[(20+(k))>>2][(20+(k))&3]
  #define WF2(k) wfv[(40+(k))>>2][(40+(k))&3]
  float bf0 = bf_l[d], bf1 = bf_l[DD + d], bf2 = bf_l[2*DD + d];
  int e = indptr[n], end = indptr[n+1];
  // depth-2 pipeline: slots A/B; src ring 4 ahead
  int sA = 0, sB = 0;
  float p0A=0,p1A=0,p2A=0,w0A=0,w1A=0,w2A=0;
  float p0B=0,p1B=0,p2B=0,w0B=0,w1B=0,w2B=0;
  float4 g1A={}, g2A={}, g1B={}, g2B={};
  if (e < end) {
    int s0 = srcs[e];
    long bb = (long)s0*DD + d;
    p0A = phi0[bb]; p1A = phi1[bb]; p2A = phi2[bb];
    w0A = vA[bb]; w1A = vA[NND+bb]; w2A = vA[2*NND+bb];
    g1A = eg1[e]; g2A = eg2[e];
  }
  if (e + 1 < end) {
    int s1v = srcs[e+1];
    long bb = (long)s1v*DD + d;
    p0B = phi0[bb]; p1B = phi1[bb]; p2B = phi2[bb];
    w0B = vA[bb]; w1B = vA[NND+bb]; w2B = vA[2*NND+bb];
    g1B = eg1[e+1]; g2B = eg2[e+1];
  }
  if (e + 2 < end) sA = srcs[e+2];
  if (e + 3 < end) sB = srcs[e+3];
  float xacc=0.f, a0=0.f, a1=0.f, a2=0.f;
#define SW_BODY(P0,P1,P2,W0,W1,W2, G1, G2, SS) \
    { float c2 = 2.0f * G1.y; \
      float rkm1 = 0.f, rk = G1.x, dot0 = 0.f, dot1 = 0.f, dot2 = 0.f; \
      _Pragma("unroll") \
      for (int k = 0; k < NB_; k++) { \
        dot0 = fmaf(rk, WF0(k), dot0); \
        dot1 = fmaf(rk, WF1(k), dot1); \
        dot2 = fmaf(rk, WF2(k), dot2); \
        float rn = fmaf(c2, rk, -rkm1); \
        rkm1 = rk; rk = rn; } \
      xacc = fmaf(P0, bf0*G1.z + G1.w*dot0, xacc); \
      float m1 = P1 * (bf1*G1.z + G1.w*dot1); \
      float m2 = P2 * (bf2*G1.z + G1.w*dot2); \
      a0 = fmaf(m1, G2.x, fmaf(m2, W0, a0)); \
      a1 = fmaf(m1, G2.y, fmaf(m2, W1, a1)); \
      a2 = fmaf(m1, G2.z, fmaf(m2, W2, a2)); \
      if (e + 2 < end) { \
        long bb = (long)SS*DD + d; \
        P0 = phi0[bb]; P1 = phi1[bb]; P2 = phi2[bb]; \
        W0 = vA[bb]; W1 = vA[NND+bb]; W2 = vA[2*NND+bb]; \
        G1 = eg1[e+2]; G2 = eg2[e+2]; } \
      if (e + 4 < end) SS = srcs[e+4]; \
      ++e; }
  while (e < end) {
    SW_BODY(p0A,p1A,p2A,w0A,w1A,w2A, g1A, g2A, sA)
    if (e >= end) break;
    SW_BODY(p0B,p1B,p2B,w0B,w1B,w2B, g1B, g2B, sB)
  }
#undef SW_BODY
  #undef WF0
  #undef WF1
  #undef WF2
  long b = (long)n*DD + d;
  x[b] += xacc;              // x becomes x_new in place
  vd[b]         = a0;
  vd[NND + b]   = a1;
  vd[2*NND + b] = a2;
}

// ---------------- muva (R20): Uv/Vv/Vn/s + a-MLP + update; sweep moved out ----------------
// Stages base+delta from global (coalesced float4), then identical MFMA phases.
// v updated IN PLACE (each block reads/writes only its own 16 rows; sweep is a
// separate kernel so no other reader of these rows exists) — v_b buffer freed for vd.
__global__ void __launch_bounds__(512, 3) muva_kernel(
    const float* __restrict__ vd, float* __restrict__ vA, float* __restrict__ x,
    const short* __restrict__ Uth, const short* __restrict__ Utl,
    const short* __restrict__ Vth, const short* __restrict__ Vtl,
    const short* __restrict__ W1h, const short* __restrict__ W1l, const float* __restrict__ b1,
    const short* __restrict__ W2h, const short* __restrict__ W2l, const float* __restrict__ b2) {
  __shared__ float smem[8896];   // 35584 B
  // shorts: VNH[48][136] @0 | VNL[48][136] @6528; overlay CATH[16][264] @0 | CATL @4224 |
  //         T2H[16][136] @8448 | T2L @10624. floats: XN[16][136] @6720 (no overlap).
  short* sms = (short*)smem;
  #define XN(r,c)   smem[6720 + (r)*136 + (c)]
  #define VNH(r,c)  sms[(r)*136 + (c)]
  #define VNL(r,c)  sms[6528 + (r)*136 + (c)]
  #define CATH(r,c) sms[(r)*264 + (c)]
  #define CATL(r,c) sms[4224 + (r)*264 + (c)]
  #define T2H(r,c)  sms[8448 + (r)*136 + (c)]
  #define T2L(r,c)  sms[10624 + (r)*136 + (c)]
  const long NND = (long)NN*DD;
  int tid = threadIdx.x;
  long nb = (long)blockIdx.x * 16;
  int lane = tid & 63, wv = tid >> 6;   // wv 0..7
  int l15 = lane & 15, q = lane >> 4;
  int dc = wv*16 + l15;                 // this wave's column slice
  // ---- stage: v_new = base + delta (split to VNH/VNL), x_new -> XN fp32 ----
  float4 cf[3];
  {
    int ch = tid * 3;                   // 1536 float4-chunks: 48 rows x 32
    #pragma unroll
    for (int j = 0; j < 3; j++) {
      int r = (ch + j) >> 5, c4 = (ch + j) & 31;
      long off = (long)(r >> 4)*NND + (nb + (r & 15))*DD + c4*4;
      float4 bs = *(const float4*)(vA + off);
      float4 dl = *(const float4*)(vd + off);
      cf[j] = make_float4(bs.x + dl.x, bs.y + dl.y, bs.z + dl.z, bs.w + dl.w);
    }
    int r = tid >> 5, c4 = tid & 31;
    *(float4*)&XN(r, c4*4) = *(const float4*)(x + (nb + r)*DD + c4*4);
  }
  float vold[4][3];
  #pragma unroll
  for (int i = 0; i < 4; i++)
    #pragma unroll
    for (int c = 0; c < 3; c++) {
      long off = (long)c*NND + (nb + q*4 + i)*DD + dc;
      vold[i][c] = vA[off] + vd[off];
    }
  {
    int ch = tid * 3;
    #pragma unroll
    for (int j = 0; j < 3; j++) {
      int r = (ch + j) >> 5, c4 = (ch + j) & 31;
      split_store4(cf[j], &VNH(r, c4*4), &VNL(r, c4*4));
    }
  }
  __syncthreads();
  // ---- phase 1: U & V projections for column-slice dc (A-fragments pre-split) ----
  v4f aU[3] = {}, aV[3] = {};
  #pragma unroll
  for (int s = 0; s < 4; s++) {
    long boff = (long)dc*128 + s*32 + q*8;
    v8s buh = *(const v8s*)(Uth + boff);
    v8s bul = *(const v8s*)(Utl + boff);
    v8s bvh = *(const v8s*)(Vth + boff);
    v8s bvl = *(const v8s*)(Vtl + boff);
    #pragma unroll
    for (int c = 0; c < 3; c++) {
      v8s ah = *(const v8s*)&VNH(c*16 + l15, s*32 + q*8);
      v8s al = *(const v8s*)&VNL(c*16 + l15, s*32 + q*8);
      MFMA3(aU[c], ah, al, buh, bul);
      MFMA3(aV[c], ah, al, bvh, bvl);
    }
  }
  float sreg[4], vn2[4];
  #pragma unroll
  for (int i = 0; i < 4; i++) {
    sreg[i] = aU[0][i]*aV[0][i] + aU[1][i]*aV[1][i] + aU[2][i]*aV[2][i];
    vn2[i]  = aV[0][i]*aV[0][i] + aV[1][i]*aV[1][i] + aV[2][i]*aV[2][i];
  }
  __syncthreads();   // all reads of VNH/VNL complete before CAT overlay
  // ---- build cat = [x_new | Vn] directly as bf16 hi/lo (split once by producer) ----
  {
    int r = tid >> 5, c4 = tid & 31;   // 512 tasks: 16 rows x 32 float4-chunks
    float4 f = *(const float4*)&XN(r, c4*4);
    split_store4(f, &CATH(r, c4*4), &CATL(r, c4*4));
  }
  #pragma unroll
  for (int i = 0; i < 4; i++) {
    short h, l;
    split2(sqrtf(vn2[i] + 1e-8f), h, l);
    CATH(q*4 + i, 128 + dc) = h;
    CATL(q*4 + i, 128 + dc) = l;
  }
  __syncthreads();
  // ---- GEMM1: t2[:, dc] = silu(cat @ Wu1 + b1), K=256; t2 written pre-split ----
  {
    v4f acc = {};
    #pragma unroll
    for (int s = 0; s < 8; s++) {
      v8s ah = *(const v8s*)&CATH(l15, s*32 + q*8);
      v8s al = *(const v8s*)&CATL(l15, s*32 + q*8);
      v8s bh = *(const v8s*)(W1h + (long)dc*256 + s*32 + q*8);
      v8s bl = *(const v8s*)(W1l + (long)dc*256 + s*32 + q*8);
      MFMA3(acc, ah, al, bh, bl);
    }
    float bb = b1[dc];
    #pragma unroll
    for (int i = 0; i < 4; i++) {
      short h, l;
      split2(silu_f(acc[i] + bb), h, l);
      T2H(q*4 + i, dc) = h;
      T2L(q*4 + i, dc) = l;
    }
  }
  __syncthreads();
  // ---- GEMM2 + epilogue ----
  {
    v4f acc[3] = {};
    #pragma unroll
    for (int s = 0; s < 4; s++) {
      v8s ah = *(const v8s*)&T2H(l15, s*32 + q*8);
      v8s al = *(const v8s*)&T2L(l15, s*32 + q*8);
      #pragma unroll
      for (int g = 0; g < 3; g++) {
        int n = g*128 + dc;                 // avv: dc, asv: 128+dc, ass: 256+dc
        v8s bh = *(const v8s*)(W2h + (long)n*128 + s*32 + q*8);
        v8s bl = *(const v8s*)(W2l + (long)n*128 + s*32 + q*8);
        MFMA3(acc[g], ah, al, bh, bl);
      }
    }
    float bavv = b2[dc], basv = b2[128 + dc], bass = b2[256 + dc];
    #pragma unroll
    for (int i = 0; i < 4; i++) {
      int lr = q*4 + i;
      long row = nb + lr;
      float avv = acc[0][i] + bavv;
      float asv = acc[1][i] + basv;
      float ass = acc[2][i] + bass;
      x[row*DD + dc] = XN(lr, dc) + ass + asv * sreg[i];   // XN = x_new fp32 (exact)
      #pragma unroll
      for (int c = 0; c < 3; c++)
        vA[(long)c*NND + row*DD + dc] = fmaf(avv, aU[c][i], vold[i][c]);  // in place
    }
  }
  #undef XN
  #undef VNH
  #undef VNL
  #undef CATH
  #undef CATL
  #undef T2H
  #undef T2L
}

// ---------------- output head + segment sum: 4 nodes/block, LDS-staged x ----------------
__global__ void __launch_bounds__(256) out_kernel(
    const float* __restrict__ x, const float* __restrict__ Wo1,
    const float* __restrict__ bo1, const float* __restrict__ Wo2,
    const float* __restrict__ bo2, const int* __restrict__ batch,
    float* __restrict__ out) {
  __shared__ float xs[4][132];
  int tid = threadIdx.x;
  long n0 = (long)blockIdx.x * 4;
  if (tid < 128) {
    int r = tid >> 5, c4 = tid & 31;
    *(float4*)&xs[r][c4*4] = *(const float4*)(x + (n0 + r)*128 + c4*4);
  }
  __syncthreads();
  int wv = tid >> 6, t = tid & 63;
  float acc = bo1[t];
  #pragma unroll 16
  for (int k = 0; k < DD; k++) acc = fmaf(xs[wv][k], Wo1[k*HH + t], acc);
  float val = silu_f(acc) * Wo2[t];
  #pragma unroll
  for (int off = 32; off > 0; off >>= 1) val += __shfl_down(val, off);
  if (t == 0) atomicAdd(&out[batch[n0 + wv]], val + bo2[0]);
}

// ---------------- launcher ----------------
extern "C" void kernel_launch(void* const* d_in, const int* in_sizes, int n_in,
                              void* d_out, int out_size, void* d_ws, size_t ws_size,
                              hipStream_t stream) {
  const int*   at_no = (const int*)d_in[0];
  const float* pos   = (const float*)d_in[1];
  const int*   ei    = (const int*)d_in[2];
  const int*   batch = (const int*)d_in[3];
  const float* emb   = (const float*)d_in[4];
  const float* Wf    = (const float*)d_in[5];
  const float* bfp   = (const float*)d_in[6];
  const float* Wm1   = (const float*)d_in[7];
  const float* bm1   = (const float*)d_in[8];
  const float* Wm2   = (const float*)d_in[9];
  const float* bm2   = (const float*)d_in[10];
  const float* U     = (const float*)d_in[11];
  const float* V     = (const float*)d_in[12];
  const float* Wu1   = (const float*)d_in[13];
  const float* bu1   = (const float*)d_in[14];
  const float* Wu2   = (const float*)d_in[15];
  const float* bu2   = (const float*)d_in[16];
  const float* Wo1   = (const float*)d_in[17];
  const float* bo1   = (const float*)d_in[18];
  const float* Wo2   = (const float*)d_in[19];
  const float* bo2   = (const float*)d_in[20];
  float* out = (float*)d_out;

  char* w = (char*)d_ws;
  auto alloc = [&](size_t bytes) -> void* {
    void* p = (void*)w;
    w += (bytes + 255) & ~(size_t)255;
    return p;
  };
  float*  x      = (float*)alloc(sizeof(float)*(size_t)NN*DD);
  float*  v      = (float*)alloc(sizeof(float)*(size_t)NN*D3);   // plane layout [3][NN][DD], in-place
  float*  vd     = (float*)alloc(sizeof(float)*(size_t)NN*D3);   // sweep v-deltas (was v_b)
  float*  t1     = (float*)alloc(sizeof(float)*(size_t)NN*DD);   // phi slice 2
  float*  phiS   = (float*)alloc(sizeof(float)*(size_t)NN*DD);   // phi slice 1
  float*  phi0   = (float*)alloc(sizeof(float)*(size_t)NN*DD);   // phi slice 0
  short*  wbh    = (short*)alloc(sizeof(short)*(size_t)3*LSZ);   // bf16-hi weights
  short*  wbl    = (short*)alloc(sizeof(short)*(size_t)3*LSZ);   // bf16-lo weights
  int*    srcs   = (int*)alloc(sizeof(int)*(size_t)ECAP);
  float4* eg1    = (float4*)alloc(sizeof(float4)*(size_t)ECAP);
  float4* eg2    = (float4*)alloc(sizeof(float4)*(size_t)ECAP);
  int*    indptr = (int*)alloc(sizeof(int)*((size_t)NN+1));
  int*    counts = (int*)alloc(sizeof(int)*(size_t)NN);
  float*  wfT    = (float*)alloc(sizeof(float)*(size_t)3*8192);  // transposed Wf [l][128][64]

  if ((size_t)(w - (char*)d_ws) > ws_size) {   // diagnostic guard: zeros => ws too small
    zero_f_kernel<<<2, 256, 0, stream>>>(out, NG_);
    return;
  }

  zero_f_kernel<<<2048, 256, 0, stream>>>(v, (long)NN*D3);
  zero_f_kernel<<<2, 256, 0, stream>>>(out, NG_);
  zero_i_kernel<<<64, 256, 0, stream>>>(counts, NN);
  init_x_kernel<<<(NN*DD + 255)/256, 256, 0, stream>>>(at_no, emb, x);
  prep_w_kernel<<<(3*LSZ + 255)/256, 256, 0, stream>>>(Wm1, Wm2, U, V, Wu1, Wu2, wbh, wbl);
  prep_wf_kernel<<<96, 256, 0, stream>>>(Wf, wfT);
  hist_kernel<<<(NE + 255)/256, 256, 0, stream>>>(ei, pos, counts);
  scan_kernel<<<1, 1024, 0, stream>>>(counts, indptr, NN);
  zero_i_kernel<<<64, 256, 0, stream>>>(counts, NN);
  fill_kernel<<<(NE + 255)/256, 256, 0, stream>>>(ei, pos, indptr, counts, srcs, eg1, eg2);

  const int MB = (NN + 31) / 32;    // 1563
  for (int l = 0; l < 3; l++) {
    const float* wfT_l = wfT + (size_t)l*8192;
    const float* bf_l  = bfp + (size_t)l*D3;
    const float* bm1_l = bm1 + (size_t)l*DD;
    const float* bm2_l = bm2 + (size_t)l*D3;
    const float* bu1_l = bu1 + (size_t)l*DD;
    const float* bu2_l = bu2 + (size_t)l*D3;
    const short* Lh = wbh + (size_t)l*LSZ;
    const short* Ll = wbl + (size_t)l*LSZ;
    const short* Wm1h = Lh,          *Wm1L = Ll;
    const short* Wm2h = Lh + 16384,  *Wm2L = Ll + 16384;
    const short* Uh   = Lh + 65536,  *UL   = Ll + 65536;
    const short* Vh   = Lh + 81920,  *VL   = Ll + 81920;
    const short* Wu1h = Lh + 98304,  *Wu1L = Ll + 98304;
    const short* Wu2h = Lh + 131072, *Wu2L = Ll + 131072;

    // fused node-MLP: x -> t2 (LDS) -> phi slices {phi0, phiS, t1}
    mlp_phi_kernel<<<MB, 512, 0, stream>>>(x, Wm1h, Wm1L, bm1_l, Wm2h, Wm2L, bm2_l,
                                           phi0, phiS, t1, NN);
    // edge sweep: x += xdelta in place; v-deltas -> vd (max-TLP, zero-LDS kernel)
    sweep_kernel<<<NN, 128, 0, stream>>>(phi0, phiS, t1, v, x, vd,
                                         srcs, eg1, eg2, indptr, wfT_l, bf_l);
    // U/V proj + a-MLP + x,v update (v in place)
    muva_kernel<<<NN/16, 512, 0, stream>>>(vd, v, x,
                                           Uh, UL, Vh, VL,
                                           Wu1h, Wu1L, bu1_l, Wu2h, Wu2L, bu2_l);
  }

  out_kernel<<<NN/4, 256, 0, stream>>>(x, Wo1, bo1, Wo2, bo2, batch, out);

  (void)in_sizes; (void)n_in; (void)out_size; (void)ws_size;
}

// Round 8
// 1745.557 us; speedup vs baseline: 2.1144x; 2.1144x over previous
//
#include <hip/hip_runtime.h>
#include <math.h>

#define NN 50000
#define NE 600000
#define ECAP 230000  // capacity for filtered edges (actual ~175K)
#define DD 128
#define D3 384
#define NB_ 20
#define HH 64
#define NG_ 512
#define LSZ 180224   // shorts per layer of transposed-bf16 weights

typedef short v8s __attribute__((ext_vector_type(8)));
typedef short v4sh __attribute__((ext_vector_type(4)));
typedef float v4f __attribute__((ext_vector_type(4)));

__device__ __forceinline__ float silu_f(float z) { return z / (1.0f + expf(-z)); }

__device__ __forceinline__ short f2bf(float f) {
  unsigned u = __float_as_uint(f);
  u += 0x7FFF + ((u >> 16) & 1);          // RNE
  return (short)(u >> 16);
}
__device__ __forceinline__ float bf2f(short s) {
  return __uint_as_float(((unsigned)(unsigned short)s) << 16);
}
__device__ __forceinline__ void split2(float x, short& h, short& l) {
  h = f2bf(x);
  l = f2bf(x - bf2f(h));
}
// split a float4 and store hi/lo as short4 (8B LDS stores)
__device__ __forceinline__ void split_store4(float4 f, short* hp, short* lp) {
  short h0,l0,h1,l1,h2,l2,h3,l3;
  split2(f.x,h0,l0); split2(f.y,h1,l1); split2(f.z,h2,l2); split2(f.w,h3,l3);
  v4sh hv = {h0,h1,h2,h3}, lv = {l0,l1,l2,l3};
  *(v4sh*)hp = hv; *(v4sh*)lp = lv;
}
// 3-term Markidis split: acc += ah@bh + al@bh + ah@bl   (proven: absmax 4.3e9)
#define MFMA3(acc, ah, al, bh, bl) \
  acc = __builtin_amdgcn_mfma_f32_16x16x32_bf16(ah, bh, acc, 0, 0, 0); \
  acc = __builtin_amdgcn_mfma_f32_16x16x32_bf16(al, bh, acc, 0, 0, 0); \
  acc = __builtin_amdgcn_mfma_f32_16x16x32_bf16(ah, bl, acc, 0, 0, 0);

// ---------------- utility ----------------
__global__ void zero_f_kernel(float* __restrict__ p, long n) {
  long i = (long)blockIdx.x * blockDim.x + threadIdx.x;
  long s = (long)gridDim.x * blockDim.x;
  for (; i < n; i += s) p[i] = 0.0f;
}

__global__ void zero_i_kernel(int* __restrict__ p, long n) {
  long i = (long)blockIdx.x * blockDim.x + threadIdx.x;
  long s = (long)gridDim.x * blockDim.x;
  for (; i < n; i += s) p[i] = 0;
}

__global__ void init_x_kernel(const int* __restrict__ at_no, const float* __restrict__ emb,
                              float* __restrict__ x) {
  int i = blockIdx.x * blockDim.x + threadIdx.x;
  if (i >= NN * DD) return;
  x[i] = emb[at_no[i >> 7] * DD + (i & 127)];
}

// ---------------- weight prep: fp32 [K][N] -> transposed bf16 hi/lo [N][K] ----------------
__global__ void prep_w_kernel(const float* __restrict__ Wm1, const float* __restrict__ Wm2,
                              const float* __restrict__ U, const float* __restrict__ V,
                              const float* __restrict__ Wu1, const float* __restrict__ Wu2,
                              short* __restrict__ hi, short* __restrict__ lo) {
  int idx = blockIdx.x * 256 + threadIdx.x;
  if (idx >= 3 * LSZ) return;
  int l = idx / LSZ, r = idx % LSZ;
  const float* src; int K, N, nk;
  if (r < 16384)       { src = Wm1 + (size_t)l*16384; K = 128; N = 128; nk = r; }
  else if (r < 65536)  { src = Wm2 + (size_t)l*49152; K = 128; N = 384; nk = r - 16384; }
  else if (r < 81920)  { src = U   + (size_t)l*16384; K = 128; N = 128; nk = r - 65536; }
  else if (r < 98304)  { src = V   + (size_t)l*16384; K = 128; N = 128; nk = r - 81920; }
  else if (r < 131072) { src = Wu1 + (size_t)l*32768; K = 256; N = 128; nk = r - 98304; }
  else                 { src = Wu2 + (size_t)l*49152; K = 128; N = 384; nk = r - 131072; }
  int n = nk / K, k = nk - n * K;
  float xx = src[(size_t)k * N + n];
  short h = f2bf(xx);
  hi[idx] = h;
  lo[idx] = f2bf(xx - bf2f(h));
}

// Wf transpose: [NB_][D3] fp32 -> wfT[128][64] per layer (c = ch*20+k, padded to 64)
// so each d-lane's 60 filter weights are one contiguous 240B region (15 x float4 loads).
__global__ void prep_wf_kernel(const float* __restrict__ Wf, float* __restrict__ wfT) {
  int idx = blockIdx.x * 256 + threadIdx.x;
  if (idx >= 3 * 8192) return;
  int l = idx / 8192, r = idx % 8192;
  int d = r >> 6, c = r & 63;
  float v = 0.0f;
  if (c < 60) {
    int ch = c / 20, k = c % 20;
    v = Wf[(size_t)l * NB_ * D3 + (size_t)k * D3 + ch * DD + d];
  }
  wfT[(size_t)l * 8192 + d * 64 + c] = v;
}

// ---------------- CSR build (dst-sorted), filtering dist>=CUTOFF edges ----------------
__global__ void hist_kernel(const int* __restrict__ ei, const float* __restrict__ pos,
                            int* __restrict__ counts) {
  int e = blockIdx.x * blockDim.x + threadIdx.x;
  if (e >= NE) return;
  int s = ei[e], d = ei[NE + e];
  float dx = pos[3*d]   - pos[3*s];
  float dy = pos[3*d+1] - pos[3*s+1];
  float dz = pos[3*d+2] - pos[3*s+2];
  float d2 = dx*dx + dy*dy + dz*dz + 1e-12f;
  if (d2 < 25.0f) atomicAdd(&counts[d], 1);
}

__global__ void scan_kernel(const int* __restrict__ counts, int* __restrict__ indptr, int n) {
  __shared__ int sm[1024];
  __shared__ int carry_s;
  if (threadIdx.x == 0) carry_s = 0;
  __syncthreads();
  for (int start = 0; start < n; start += 1024) {
    int i = start + (int)threadIdx.x;
    int val = (i < n) ? counts[i] : 0;
    sm[threadIdx.x] = val;
    __syncthreads();
    for (int off = 1; off < 1024; off <<= 1) {
      int t = (threadIdx.x >= (unsigned)off) ? sm[threadIdx.x - off] : 0;
      __syncthreads();
      sm[threadIdx.x] += t;
      __syncthreads();
    }
    int c = carry_s;
    if (i < n) indptr[i] = c + sm[threadIdx.x] - val;
    __syncthreads();
    if (threadIdx.x == 0) carry_s = c + sm[1023];
    __syncthreads();
  }
  if (threadIdx.x == 0) indptr[n] = carry_s;
}

__global__ void fill_kernel(const int* __restrict__ ei, const float* __restrict__ pos,
                            const int* __restrict__ indptr, int* __restrict__ cursor,
                            int* __restrict__ srcs, float4* __restrict__ eg1,
                            float4* __restrict__ eg2) {
  int e = blockIdx.x * blockDim.x + threadIdx.x;
  if (e >= NE) return;
  int s = ei[e], d = ei[NE + e];
  float dx = pos[3*d]   - pos[3*s];
  float dy = pos[3*d+1] - pos[3*s+1];
  float dz = pos[3*d+2] - pos[3*s+2];
  float d2 = dx*dx + dy*dy + dz*dz + 1e-12f;
  if (d2 < 25.0f) {
    int p = atomicAdd(&cursor[d], 1);
    int slot = indptr[d] + p;
    float dist = sqrtf(d2);
    float inv = 1.0f / dist;
    float wang = 0.62831853071795864769f * dist;   // pi*dist/CUTOFF
    float s1 = __sinf(wang), c1 = __cosf(wang);
    float fc = 0.5f * (c1 + 1.0f);
    srcs[slot] = s;
    eg1[slot] = make_float4(s1, c1, fc, fc * inv);
    eg2[slot] = make_float4(dx * inv, dy * inv, dz * inv, 0.0f);
  }
}

// ---------------- fused node MLP: phi = silu(x@Wm1+b1)@Wm2+b2, tri-slice out ----------------
// Row-local chain; t2 never leaves LDS. 512 thr / 8 waves, 32 rows/block.
__global__ void __launch_bounds__(512) mlp_phi_kernel(
    const float* __restrict__ x,
    const short* __restrict__ W1h, const short* __restrict__ W1l, const float* __restrict__ b1,
    const short* __restrict__ W2h, const short* __restrict__ W2l, const float* __restrict__ b2,
    float* __restrict__ C0, float* __restrict__ C1, float* __restrict__ C2, int M) {
  __shared__ short sm[4 * 32 * 136];   // XH | XL | TH | TL
  #define XH_(r,c) sm[(r)*136 + (c)]
  #define XL_(r,c) sm[4352 + (r)*136 + (c)]
  #define TH_(r,c) sm[8704 + (r)*136 + (c)]
  #define TL_(r,c) sm[13056 + (r)*136 + (c)]
  int tid = threadIdx.x;
  long r0 = (long)blockIdx.x * 32;
  #pragma unroll
  for (int i = 0; i < 2; i++) {
    int lin = i*512 + tid;
    int r = lin >> 5, c4 = lin & 31;
    long row = r0 + r; if (row >= M) row = M - 1;
    float4 f = *(const float4*)(x + row*128 + c4*4);
    split_store4(f, &XH_(r, c4*4), &XL_(r, c4*4));
  }
  __syncthreads();
  int lane = tid & 63, wv = tid >> 6;   // wv 0..7
  int l15 = lane & 15, q = lane >> 4;
  // GEMM1: t2 = silu(x@Wm1 + b1); wave w owns cols w*16+l15
  {
    int n = wv*16 + l15;
    v4f acc[2] = {};
    #pragma unroll
    for (int s = 0; s < 4; s++) {
      v8s bh = *(const v8s*)(W1h + (long)n*128 + s*32 + q*8);
      v8s bl = *(const v8s*)(W1l + (long)n*128 + s*32 + q*8);
      #pragma unroll
      for (int mt = 0; mt < 2; mt++) {
        v8s ah = *(const v8s*)&XH_(mt*16 + l15, s*32 + q*8);
        v8s al = *(const v8s*)&XL_(mt*16 + l15, s*32 + q*8);
        MFMA3(acc[mt], ah, al, bh, bl);
      }
    }
    float bb = b1[n];
    #pragma unroll
    for (int mt = 0; mt < 2; mt++)
      #pragma unroll
      for (int i = 0; i < 4; i++) {
        short h, l;
        split2(silu_f(acc[mt][i] + bb), h, l);
        TH_(mt*16 + q*4 + i, n) = h;
        TL_(mt*16 + q*4 + i, n) = l;
      }
  }
  __syncthreads();
  // GEMM2: phi = t2@Wm2 + b2 (384 cols; wave w -> n-tiles w*3..w*3+2)
  v4f acc[2][3] = {};
  #pragma unroll
  for (int s = 0; s < 4; s++) {
    v8s ah[2], al[2];
    #pragma unroll
    for (int mt = 0; mt < 2; mt++) {
      ah[mt] = *(const v8s*)&TH_(mt*16 + l15, s*32 + q*8);
      al[mt] = *(const v8s*)&TL_(mt*16 + l15, s*32 + q*8);
    }
    #pragma unroll
    for (int j = 0; j < 3; j++) {
      int n = (wv*3 + j)*16 + l15;
      v8s bh = *(const v8s*)(W2h + (long)n*128 + s*32 + q*8);
      v8s bl = *(const v8s*)(W2l + (long)n*128 + s*32 + q*8);
      #pragma unroll
      for (int mt = 0; mt < 2; mt++) { MFMA3(acc[mt][j], ah[mt], al[mt], bh, bl); }
    }
  }
  #pragma unroll
  for (int j = 0; j < 3; j++) {
    int n = (wv*3 + j)*16 + l15;
    int sl = n >> 7, col = n & 127;
    float* C = (sl == 0) ? C0 : (sl == 1) ? C1 : C2;
    float bb = b2[n];
    #pragma unroll
    for (int mt = 0; mt < 2; mt++)
      #pragma unroll
      for (int i = 0; i < 4; i++) {
        long row = r0 + mt*16 + q*4 + i;
        if (row < M) C[row*128 + col] = acc[mt][j][i] + bb;
      }
  }
  #undef XH_
  #undef XL_
  #undef TH_
  #undef TL_
}

// ---------------- R21: dedicated edge-sweep kernel (max-TLP gather engine) ----------------
// One node per 128-thread block, ZERO LDS. R21 fix vs R20: __launch_bounds__(128,4)
// (was (128,8) -> 32-VGPR budget -> wfv+slots spilled to SCRATCH -> 1.7GB of HBM spill
// traffic, 830us/layer). Peak live state ~120 regs needs the 128-reg budget; 4 waves/EU
// = 16 waves/CU still exceeds the fused kernel's 13 and has no LDS barrier coupling.
__global__ void __launch_bounds__(128, 4) sweep_kernel(
    const float* __restrict__ phi0, const float* __restrict__ phi1,
    const float* __restrict__ phi2, const float* __restrict__ vA,
    float* __restrict__ x, float* __restrict__ vd,
    const int* __restrict__ srcs, const float4* __restrict__ eg1,
    const float4* __restrict__ eg2, const int* __restrict__ indptr,
    const float* __restrict__ wfT_l, const float* __restrict__ bf_l) {
  const long NND = (long)NN*DD;
  int n = blockIdx.x;
  int d = threadIdx.x;
  // per-lane filter weights: 15 x float4 from contiguous 240B (register-resident at
  // the 128-reg budget; remat from L1 acceptable if allocator chooses)
  v4f wfv[15];
  {
    const float* wrow = wfT_l + d*64;
    #pragma unroll
    for (int j = 0; j < 15; j++) wfv[j] = *(const v4f*)(wrow + j*4);
  }
  #define WF0(k) wfv[(k)>>2][(k)&3]
  #define WF1(k) wfv[(20+(k))>>2][(20+(k))&3]
  #define WF2(k) wfv[(40+(k))>>2][(40+(k))&3]
  float bf0 = bf_l[d], bf1 = bf_l[DD + d], bf2 = bf_l[2*DD + d];
  int e = indptr[n], end = indptr[n+1];
  // depth-2 pipeline: slots A/B; src ring 4 ahead
  int sA = 0, sB = 0;
  float p0A=0,p1A=0,p2A=0,w0A=0,w1A=0,w2A=0;
  float p0B=0,p1B=0,p2B=0,w0B=0,w1B=0,w2B=0;
  float4 g1A={}, g2A={}, g1B={}, g2B={};
  if (e < end) {
    int s0 = srcs[e];
    long bb = (long)s0*DD + d;
    p0A = phi0[bb]; p1A = phi1[bb]; p2A = phi2[bb];
    w0A = vA[bb]; w1A = vA[NND+bb]; w2A = vA[2*NND+bb];
    g1A = eg1[e]; g2A = eg2[e];
  }
  if (e + 1 < end) {
    int s1v = srcs[e+1];
    long bb = (long)s1v*DD + d;
    p0B = phi0[bb]; p1B = phi1[bb]; p2B = phi2[bb];
    w0B = vA[bb]; w1B = vA[NND+bb]; w2B = vA[2*NND+bb];
    g1B = eg1[e+1]; g2B = eg2[e+1];
  }
  if (e + 2 < end) sA = srcs[e+2];
  if (e + 3 < end) sB = srcs[e+3];
  float xacc=0.f, a0=0.f, a1=0.f, a2=0.f;
#define SW_BODY(P0,P1,P2,W0,W1,W2, G1, G2, SS) \
    { float c2 = 2.0f * G1.y; \
      float rkm1 = 0.f, rk = G1.x, dot0 = 0.f, dot1 = 0.f, dot2 = 0.f; \
      _Pragma("unroll") \
      for (int k = 0; k < NB_; k++) { \
        dot0 = fmaf(rk, WF0(k), dot0); \
        dot1 = fmaf(rk, WF1(k), dot1); \
        dot2 = fmaf(rk, WF2(k), dot2); \
        float rn = fmaf(c2, rk, -rkm1); \
        rkm1 = rk; rk = rn; } \
      xacc = fmaf(P0, bf0*G1.z + G1.w*dot0, xacc); \
      float m1 = P1 * (bf1*G1.z + G1.w*dot1); \
      float m2 = P2 * (bf2*G1.z + G1.w*dot2); \
      a0 = fmaf(m1, G2.x, fmaf(m2, W0, a0)); \
      a1 = fmaf(m1, G2.y, fmaf(m2, W1, a1)); \
      a2 = fmaf(m1, G2.z, fmaf(m2, W2, a2)); \
      if (e + 2 < end) { \
        long bb = (long)SS*DD + d; \
        P0 = phi0[bb]; P1 = phi1[bb]; P2 = phi2[bb]; \
        W0 = vA[bb]; W1 = vA[NND+bb]; W2 = vA[2*NND+bb]; \
        G1 = eg1[e+2]; G2 = eg2[e+2]; } \
      if (e + 4 < end) SS = srcs[e+4]; \
      ++e; }
  while (e < end) {
    SW_BODY(p0A,p1A,p2A,w0A,w1A,w2A, g1A, g2A, sA)
    if (e >= end) break;
    SW_BODY(p0B,p1B,p2B,w0B,w1B,w2B, g1B, g2B, sB)
  }
#undef SW_BODY
  #undef WF0
  #undef WF1
  #undef WF2
  long b = (long)n*DD + d;
  x[b] += xacc;              // x becomes x_new in place
  vd[b]         = a0;
  vd[NND + b]   = a1;
  vd[2*NND + b] = a2;
}

// ---------------- muva (R21): Uv/Vv/Vn/s + a-MLP + update; sweep moved out ----------------
// Stages base+delta from global (coalesced float4), then identical MFMA phases.
// v updated IN PLACE (each block reads/writes only its own 16 rows; sweep is a
// separate kernel so no other reader of these rows exists) — v_b buffer freed for vd.
__global__ void __launch_bounds__(512, 3) muva_kernel(
    const float* __restrict__ vd, float* __restrict__ vA, float* __restrict__ x,
    const short* __restrict__ Uth, const short* __restrict__ Utl,
    const short* __restrict__ Vth, const short* __restrict__ Vtl,
    const short* __restrict__ W1h, const short* __restrict__ W1l, const float* __restrict__ b1,
    const short* __restrict__ W2h, const short* __restrict__ W2l, const float* __restrict__ b2) {
  __shared__ float smem[8896];   // 35584 B
  // shorts: VNH[48][136] @0 | VNL[48][136] @6528; overlay CATH[16][264] @0 | CATL @4224 |
  //         T2H[16][136] @8448 | T2L @10624. floats: XN[16][136] @6720 (no overlap).
  short* sms = (short*)smem;
  #define XN(r,c)   smem[6720 + (r)*136 + (c)]
  #define VNH(r,c)  sms[(r)*136 + (c)]
  #define VNL(r,c)  sms[6528 + (r)*136 + (c)]
  #define CATH(r,c) sms[(r)*264 + (c)]
  #define CATL(r,c) sms[4224 + (r)*264 + (c)]
  #define T2H(r,c)  sms[8448 + (r)*136 + (c)]
  #define T2L(r,c)  sms[10624 + (r)*136 + (c)]
  const long NND = (long)NN*DD;
  int tid = threadIdx.x;
  long nb = (long)blockIdx.x * 16;
  int lane = tid & 63, wv = tid >> 6;   // wv 0..7
  int l15 = lane & 15, q = lane >> 4;
  int dc = wv*16 + l15;                 // this wave's column slice
  // ---- stage: v_new = base + delta (split to VNH/VNL), x_new -> XN fp32 ----
  float4 cf[3];
  {
    int ch = tid * 3;                   // 1536 float4-chunks: 48 rows x 32
    #pragma unroll
    for (int j = 0; j < 3; j++) {
      int r = (ch + j) >> 5, c4 = (ch + j) & 31;
      long off = (long)(r >> 4)*NND + (nb + (r & 15))*DD + c4*4;
      float4 bs = *(const float4*)(vA + off);
      float4 dl = *(const float4*)(vd + off);
      cf[j] = make_float4(bs.x + dl.x, bs.y + dl.y, bs.z + dl.z, bs.w + dl.w);
    }
    int r = tid >> 5, c4 = tid & 31;
    *(float4*)&XN(r, c4*4) = *(const float4*)(x + (nb + r)*DD + c4*4);
  }
  float vold[4][3];
  #pragma unroll
  for (int i = 0; i < 4; i++)
    #pragma unroll
    for (int c = 0; c < 3; c++) {
      long off = (long)c*NND + (nb + q*4 + i)*DD + dc;
      vold[i][c] = vA[off] + vd[off];
    }
  {
    int ch = tid * 3;
    #pragma unroll
    for (int j = 0; j < 3; j++) {
      int r = (ch + j) >> 5, c4 = (ch + j) & 31;
      split_store4(cf[j], &VNH(r, c4*4), &VNL(r, c4*4));
    }
  }
  __syncthreads();
  // ---- phase 1: U & V projections for column-slice dc (A-fragments pre-split) ----
  v4f aU[3] = {}, aV[3] = {};
  #pragma unroll
  for (int s = 0; s < 4; s++) {
    long boff = (long)dc*128 + s*32 + q*8;
    v8s buh = *(const v8s*)(Uth + boff);
    v8s bul = *(const v8s*)(Utl + boff);
    v8s bvh = *(const v8s*)(Vth + boff);
    v8s bvl = *(const v8s*)(Vtl + boff);
    #pragma unroll
    for (int c = 0; c < 3; c++) {
      v8s ah = *(const v8s*)&VNH(c*16 + l15, s*32 + q*8);
      v8s al = *(const v8s*)&VNL(c*16 + l15, s*32 + q*8);
      MFMA3(aU[c], ah, al, buh, bul);
      MFMA3(aV[c], ah, al, bvh, bvl);
    }
  }
  float sreg[4], vn2[4];
  #pragma unroll
  for (int i = 0; i < 4; i++) {
    sreg[i] = aU[0][i]*aV[0][i] + aU[1][i]*aV[1][i] + aU[2][i]*aV[2][i];
    vn2[i]  = aV[0][i]*aV[0][i] + aV[1][i]*aV[1][i] + aV[2][i]*aV[2][i];
  }
  __syncthreads();   // all reads of VNH/VNL complete before CAT overlay
  // ---- build cat = [x_new | Vn] directly as bf16 hi/lo (split once by producer) ----
  {
    int r = tid >> 5, c4 = tid & 31;   // 512 tasks: 16 rows x 32 float4-chunks
    float4 f = *(const float4*)&XN(r, c4*4);
    split_store4(f, &CATH(r, c4*4), &CATL(r, c4*4));
  }
  #pragma unroll
  for (int i = 0; i < 4; i++) {
    short h, l;
    split2(sqrtf(vn2[i] + 1e-8f), h, l);
    CATH(q*4 + i, 128 + dc) = h;
    CATL(q*4 + i, 128 + dc) = l;
  }
  __syncthreads();
  // ---- GEMM1: t2[:, dc] = silu(cat @ Wu1 + b1), K=256; t2 written pre-split ----
  {
    v4f acc = {};
    #pragma unroll
    for (int s = 0; s < 8; s++) {
      v8s ah = *(const v8s*)&CATH(l15, s*32 + q*8);
      v8s al = *(const v8s*)&CATL(l15, s*32 + q*8);
      v8s bh = *(const v8s*)(W1h + (long)dc*256 + s*32 + q*8);
      v8s bl = *(const v8s*)(W1l + (long)dc*256 + s*32 + q*8);
      MFMA3(acc, ah, al, bh, bl);
    }
    float bb = b1[dc];
    #pragma unroll
    for (int i = 0; i < 4; i++) {
      short h, l;
      split2(silu_f(acc[i] + bb), h, l);
      T2H(q*4 + i, dc) = h;
      T2L(q*4 + i, dc) = l;
    }
  }
  __syncthreads();
  // ---- GEMM2 + epilogue ----
  {
    v4f acc[3] = {};
    #pragma unroll
    for (int s = 0; s < 4; s++) {
      v8s ah = *(const v8s*)&T2H(l15, s*32 + q*8);
      v8s al = *(const v8s*)&T2L(l15, s*32 + q*8);
      #pragma unroll
      for (int g = 0; g < 3; g++) {
        int n = g*128 + dc;                 // avv: dc, asv: 128+dc, ass: 256+dc
        v8s bh = *(const v8s*)(W2h + (long)n*128 + s*32 + q*8);
        v8s bl = *(const v8s*)(W2l + (long)n*128 + s*32 + q*8);
        MFMA3(acc[g], ah, al, bh, bl);
      }
    }
    float bavv = b2[dc], basv = b2[128 + dc], bass = b2[256 + dc];
    #pragma unroll
    for (int i = 0; i < 4; i++) {
      int lr = q*4 + i;
      long row = nb + lr;
      float avv = acc[0][i] + bavv;
      float asv = acc[1][i] + basv;
      float ass = acc[2][i] + bass;
      x[row*DD + dc] = XN(lr, dc) + ass + asv * sreg[i];   // XN = x_new fp32 (exact)
      #pragma unroll
      for (int c = 0; c < 3; c++)
        vA[(long)c*NND + row*DD + dc] = fmaf(avv, aU[c][i], vold[i][c]);  // in place
    }
  }
  #undef XN
  #undef VNH
  #undef VNL
  #undef CATH
  #undef CATL
  #undef T2H
  #undef T2L
}

// ---------------- output head + segment sum: 4 nodes/block, LDS-staged x ----------------
__global__ void __launch_bounds__(256) out_kernel(
    const float* __restrict__ x, const float* __restrict__ Wo1,
    const float* __restrict__ bo1, const float* __restrict__ Wo2,
    const float* __restrict__ bo2, const int* __restrict__ batch,
    float* __restrict__ out) {
  __shared__ float xs[4][132];
  int tid = threadIdx.x;
  long n0 = (long)blockIdx.x * 4;
  if (tid < 128) {
    int r = tid >> 5, c4 = tid & 31;
    *(float4*)&xs[r][c4*4] = *(const float4*)(x + (n0 + r)*128 + c4*4);
  }
  __syncthreads();
  int wv = tid >> 6, t = tid & 63;
  float acc = bo1[t];
  #pragma unroll 16
  for (int k = 0; k < DD; k++) acc = fmaf(xs[wv][k], Wo1[k*HH + t], acc);
  float val = silu_f(acc) * Wo2[t];
  #pragma unroll
  for (int off = 32; off > 0; off >>= 1) val += __shfl_down(val, off);
  if (t == 0) atomicAdd(&out[batch[n0 + wv]], val + bo2[0]);
}

// ---------------- launcher ----------------
extern "C" void kernel_launch(void* const* d_in, const int* in_sizes, int n_in,
                              void* d_out, int out_size, void* d_ws, size_t ws_size,
                              hipStream_t stream) {
  const int*   at_no = (const int*)d_in[0];
  const float* pos   = (const float*)d_in[1];
  const int*   ei    = (const int*)d_in[2];
  const int*   batch = (const int*)d_in[3];
  const float* emb   = (const float*)d_in[4];
  const float* Wf    = (const float*)d_in[5];
  const float* bfp   = (const float*)d_in[6];
  const float* Wm1   = (const float*)d_in[7];
  const float* bm1   = (const float*)d_in[8];
  const float* Wm2   = (const float*)d_in[9];
  const float* bm2   = (const float*)d_in[10];
  const float* U     = (const float*)d_in[11];
  const float* V     = (const float*)d_in[12];
  const float* Wu1   = (const float*)d_in[13];
  const float* bu1   = (const float*)d_in[14];
  const float* Wu2   = (const float*)d_in[15];
  const float* bu2   = (const float*)d_in[16];
  const float* Wo1   = (const float*)d_in[17];
  const float* bo1   = (const float*)d_in[18];
  const float* Wo2   = (const float*)d_in[19];
  const float* bo2   = (const float*)d_in[20];
  float* out = (float*)d_out;

  char* w = (char*)d_ws;
  auto alloc = [&](size_t bytes) -> void* {
    void* p = (void*)w;
    w += (bytes + 255) & ~(size_t)255;
    return p;
  };
  float*  x      = (float*)alloc(sizeof(float)*(size_t)NN*DD);
  float*  v      = (float*)alloc(sizeof(float)*(size_t)NN*D3);   // plane layout [3][NN][DD], in-place
  float*  vd     = (float*)alloc(sizeof(float)*(size_t)NN*D3);   // sweep v-deltas (was v_b)
  float*  t1     = (float*)alloc(sizeof(float)*(size_t)NN*DD);   // phi slice 2
  float*  phiS   = (float*)alloc(sizeof(float)*(size_t)NN*DD);   // phi slice 1
  float*  phi0   = (float*)alloc(sizeof(float)*(size_t)NN*DD);   // phi slice 0
  short*  wbh    = (short*)alloc(sizeof(short)*(size_t)3*LSZ);   // bf16-hi weights
  short*  wbl    = (short*)alloc(sizeof(short)*(size_t)3*LSZ);   // bf16-lo weights
  int*    srcs   = (int*)alloc(sizeof(int)*(size_t)ECAP);
  float4* eg1    = (float4*)alloc(sizeof(float4)*(size_t)ECAP);
  float4* eg2    = (float4*)alloc(sizeof(float4)*(size_t)ECAP);
  int*    indptr = (int*)alloc(sizeof(int)*((size_t)NN+1));
  int*    counts = (int*)alloc(sizeof(int)*(size_t)NN);
  float*  wfT    = (float*)alloc(sizeof(float)*(size_t)3*8192);  // transposed Wf [l][128][64]

  if ((size_t)(w - (char*)d_ws) > ws_size) {   // diagnostic guard: zeros => ws too small
    zero_f_kernel<<<2, 256, 0, stream>>>(out, NG_);
    return;
  }

  zero_f_kernel<<<2048, 256, 0, stream>>>(v, (long)NN*D3);
  zero_f_kernel<<<2, 256, 0, stream>>>(out, NG_);
  zero_i_kernel<<<64, 256, 0, stream>>>(counts, NN);
  init_x_kernel<<<(NN*DD + 255)/256, 256, 0, stream>>>(at_no, emb, x);
  prep_w_kernel<<<(3*LSZ + 255)/256, 256, 0, stream>>>(Wm1, Wm2, U, V, Wu1, Wu2, wbh, wbl);
  prep_wf_kernel<<<96, 256, 0, stream>>>(Wf, wfT);
  hist_kernel<<<(NE + 255)/256, 256, 0, stream>>>(ei, pos, counts);
  scan_kernel<<<1, 1024, 0, stream>>>(counts, indptr, NN);
  zero_i_kernel<<<64, 256, 0, stream>>>(counts, NN);
  fill_kernel<<<(NE + 255)/256, 256, 0, stream>>>(ei, pos, indptr, counts, srcs, eg1, eg2);

  const int MB = (NN + 31) / 32;    // 1563
  for (int l = 0; l < 3; l++) {
    const float* wfT_l = wfT + (size_t)l*8192;
    const float* bf_l  = bfp + (size_t)l*D3;
    const float* bm1_l = bm1 + (size_t)l*DD;
    const float* bm2_l = bm2 + (size_t)l*D3;
    const float* bu1_l = bu1 + (size_t)l*DD;
    const float* bu2_l = bu2 + (size_t)l*D3;
    const short* Lh = wbh + (size_t)l*LSZ;
    const short* Ll = wbl + (size_t)l*LSZ;
    const short* Wm1h = Lh,          *Wm1L = Ll;
    const short* Wm2h = Lh + 16384,  *Wm2L = Ll + 16384;
    const short* Uh   = Lh + 65536,  *UL   = Ll + 65536;
    const short* Vh   = Lh + 81920,  *VL   = Ll + 81920;
    const short* Wu1h = Lh + 98304,  *Wu1L = Ll + 98304;
    const short* Wu2h = Lh + 131072, *Wu2L = Ll + 131072;

    // fused node-MLP: x -> t2 (LDS) -> phi slices {phi0, phiS, t1}
    mlp_phi_kernel<<<MB, 512, 0, stream>>>(x, Wm1h, Wm1L, bm1_l, Wm2h, Wm2L, bm2_l,
                                           phi0, phiS, t1, NN);
    // edge sweep: x += xdelta in place; v-deltas -> vd (max-TLP, zero-LDS kernel)
    sweep_kernel<<<NN, 128, 0, stream>>>(phi0, phiS, t1, v, x, vd,
                                         srcs, eg1, eg2, indptr, wfT_l, bf_l);
    // U/V proj + a-MLP + x,v update (v in place)
    muva_kernel<<<NN/16, 512, 0, stream>>>(vd, v, x,
                                           Uh, UL, Vh, VL,
                                           Wu1h, Wu1L, bu1_l, Wu2h, Wu2L, bu2_l);
  }

  out_kernel<<<NN/4, 256, 0, stream>>>(x, Wo1, bo1, Wo2, bo2, batch, out);

  (void)in_sizes; (void)n_in; (void)out_size; (void)ws_size;
}

// Round 10
// 1295.123 us; speedup vs baseline: 2.8498x; 1.3478x over previous
//
#include <hip/hip_runtime.h>
#include <math.h>

#define NN 50000
#define NE 600000
#define ECAP 230000  // capacity for filtered edges (actual ~175K)
#define DD 128
#define D3 384
#define NB_ 20
#define HH 64
#define NG_ 512
#define LSZ 180224   // shorts per layer of transposed-bf16 weights

typedef short v8s __attribute__((ext_vector_type(8)));
typedef short v4sh __attribute__((ext_vector_type(4)));
typedef float v4f __attribute__((ext_vector_type(4)));

__device__ __forceinline__ float silu_f(float z) { return z / (1.0f + expf(-z)); }

__device__ __forceinline__ short f2bf(float f) {
  unsigned u = __float_as_uint(f);
  u += 0x7FFF + ((u >> 16) & 1);          // RNE
  return (short)(u >> 16);
}
__device__ __forceinline__ float bf2f(short s) {
  return __uint_as_float(((unsigned)(unsigned short)s) << 16);
}
__device__ __forceinline__ void split2(float x, short& h, short& l) {
  h = f2bf(x);
  l = f2bf(x - bf2f(h));
}
// split a float4 and store hi/lo as short4 (8B LDS stores)
__device__ __forceinline__ void split_store4(float4 f, short* hp, short* lp) {
  short h0,l0,h1,l1,h2,l2,h3,l3;
  split2(f.x,h0,l0); split2(f.y,h1,l1); split2(f.z,h2,l2); split2(f.w,h3,l3);
  v4sh hv = {h0,h1,h2,h3}, lv = {l0,l1,l2,l3};
  *(v4sh*)hp = hv; *(v4sh*)lp = lv;
}
// 3-term Markidis split: acc += ah@bh + al@bh + ah@bl   (proven: absmax 4.3e9)
#define MFMA3(acc, ah, al, bh, bl) \
  acc = __builtin_amdgcn_mfma_f32_16x16x32_bf16(ah, bh, acc, 0, 0, 0); \
  acc = __builtin_amdgcn_mfma_f32_16x16x32_bf16(al, bh, acc, 0, 0, 0); \
  acc = __builtin_amdgcn_mfma_f32_16x16x32_bf16(ah, bl, acc, 0, 0, 0);

// ---------------- utility ----------------
__global__ void zero_f_kernel(float* __restrict__ p, long n) {
  long i = (long)blockIdx.x * blockDim.x + threadIdx.x;
  long s = (long)gridDim.x * blockDim.x;
  for (; i < n; i += s) p[i] = 0.0f;
}

__global__ void zero_i_kernel(int* __restrict__ p, long n) {
  long i = (long)blockIdx.x * blockDim.x + threadIdx.x;
  long s = (long)gridDim.x * blockDim.x;
  for (; i < n; i += s) p[i] = 0;
}

__global__ void init_x_kernel(const int* __restrict__ at_no, const float* __restrict__ emb,
                              float* __restrict__ x) {
  int i = blockIdx.x * blockDim.x + threadIdx.x;
  if (i >= NN * DD) return;
  x[i] = emb[at_no[i >> 7] * DD + (i & 127)];
}

// ---------------- weight prep: fp32 [K][N] -> transposed bf16 hi/lo [N][K] ----------------
__global__ void prep_w_kernel(const float* __restrict__ Wm1, const float* __restrict__ Wm2,
                              const float* __restrict__ U, const float* __restrict__ V,
                              const float* __restrict__ Wu1, const float* __restrict__ Wu2,
                              short* __restrict__ hi, short* __restrict__ lo) {
  int idx = blockIdx.x * 256 + threadIdx.x;
  if (idx >= 3 * LSZ) return;
  int l = idx / LSZ, r = idx % LSZ;
  const float* src; int K, N, nk;
  if (r < 16384)       { src = Wm1 + (size_t)l*16384; K = 128; N = 128; nk = r; }
  else if (r < 65536)  { src = Wm2 + (size_t)l*49152; K = 128; N = 384; nk = r - 16384; }
  else if (r < 81920)  { src = U   + (size_t)l*16384; K = 128; N = 128; nk = r - 65536; }
  else if (r < 98304)  { src = V   + (size_t)l*16384; K = 128; N = 128; nk = r - 81920; }
  else if (r < 131072) { src = Wu1 + (size_t)l*32768; K = 256; N = 128; nk = r - 98304; }
  else                 { src = Wu2 + (size_t)l*49152; K = 128; N = 384; nk = r - 131072; }
  int n = nk / K, k = nk - n * K;
  float xx = src[(size_t)k * N + n];
  short h = f2bf(xx);
  hi[idx] = h;
  lo[idx] = f2bf(xx - bf2f(h));
}

// ---------------- CSR build (dst-sorted), filtering dist>=CUTOFF edges ----------------
__global__ void hist_kernel(const int* __restrict__ ei, const float* __restrict__ pos,
                            int* __restrict__ counts) {
  int e = blockIdx.x * blockDim.x + threadIdx.x;
  if (e >= NE) return;
  int s = ei[e], d = ei[NE + e];
  float dx = pos[3*d]   - pos[3*s];
  float dy = pos[3*d+1] - pos[3*s+1];
  float dz = pos[3*d+2] - pos[3*s+2];
  float d2 = dx*dx + dy*dy + dz*dz + 1e-12f;
  if (d2 < 25.0f) atomicAdd(&counts[d], 1);
}

__global__ void scan_kernel(const int* __restrict__ counts, int* __restrict__ indptr, int n) {
  __shared__ int sm[1024];
  __shared__ int carry_s;
  if (threadIdx.x == 0) carry_s = 0;
  __syncthreads();
  for (int start = 0; start < n; start += 1024) {
    int i = start + (int)threadIdx.x;
    int val = (i < n) ? counts[i] : 0;
    sm[threadIdx.x] = val;
    __syncthreads();
    for (int off = 1; off < 1024; off <<= 1) {
      int t = (threadIdx.x >= (unsigned)off) ? sm[threadIdx.x - off] : 0;
      __syncthreads();
      sm[threadIdx.x] += t;
      __syncthreads();
    }
    int c = carry_s;
    if (i < n) indptr[i] = c + sm[threadIdx.x] - val;
    __syncthreads();
    if (threadIdx.x == 0) carry_s = c + sm[1023];
    __syncthreads();
  }
  if (threadIdx.x == 0) indptr[n] = carry_s;
}

__global__ void fill_kernel(const int* __restrict__ ei, const float* __restrict__ pos,
                            const int* __restrict__ indptr, int* __restrict__ cursor,
                            int* __restrict__ srcs, float4* __restrict__ eg1,
                            float4* __restrict__ eg2) {
  int e = blockIdx.x * blockDim.x + threadIdx.x;
  if (e >= NE) return;
  int s = ei[e], d = ei[NE + e];
  float dx = pos[3*d]   - pos[3*s];
  float dy = pos[3*d+1] - pos[3*s+1];
  float dz = pos[3*d+2] - pos[3*s+2];
  float d2 = dx*dx + dy*dy + dz*dz + 1e-12f;
  if (d2 < 25.0f) {
    int p = atomicAdd(&cursor[d], 1);
    int slot = indptr[d] + p;
    float dist = sqrtf(d2);
    float inv = 1.0f / dist;
    float wang = 0.62831853071795864769f * dist;   // pi*dist/CUTOFF
    float s1 = __sinf(wang), c1 = __cosf(wang);
    float fc = 0.5f * (c1 + 1.0f);
    srcs[slot] = s;
    eg1[slot] = make_float4(s1, c1, fc, fc * inv);
    eg2[slot] = make_float4(dx * inv, dy * inv, dz * inv, 0.0f);
  }
}

// ---------------- fused node MLP: phi = silu(x@Wm1+b1)@Wm2+b2, tri-slice out ----------------
// Row-local chain; t2 never leaves LDS. 512 thr / 8 waves, 32 rows/block.
__global__ void __launch_bounds__(512) mlp_phi_kernel(
    const float* __restrict__ x,
    const short* __restrict__ W1h, const short* __restrict__ W1l, const float* __restrict__ b1,
    const short* __restrict__ W2h, const short* __restrict__ W2l, const float* __restrict__ b2,
    float* __restrict__ C0, float* __restrict__ C1, float* __restrict__ C2, int M) {
  __shared__ short sm[4 * 32 * 136];   // XH | XL | TH | TL
  #define XH_(r,c) sm[(r)*136 + (c)]
  #define XL_(r,c) sm[4352 + (r)*136 + (c)]
  #define TH_(r,c) sm[8704 + (r)*136 + (c)]
  #define TL_(r,c) sm[13056 + (r)*136 + (c)]
  int tid = threadIdx.x;
  long r0 = (long)blockIdx.x * 32;
  #pragma unroll
  for (int i = 0; i < 2; i++) {
    int lin = i*512 + tid;
    int r = lin >> 5, c4 = lin & 31;
    long row = r0 + r; if (row >= M) row = M - 1;
    float4 f = *(const float4*)(x + row*128 + c4*4);
    split_store4(f, &XH_(r, c4*4), &XL_(r, c4*4));
  }
  __syncthreads();
  int lane = tid & 63, wv = tid >> 6;   // wv 0..7
  int l15 = lane & 15, q = lane >> 4;
  // GEMM1: t2 = silu(x@Wm1 + b1); wave w owns cols w*16+l15
  {
    int n = wv*16 + l15;
    v4f acc[2] = {};
    #pragma unroll
    for (int s = 0; s < 4; s++) {
      v8s bh = *(const v8s*)(W1h + (long)n*128 + s*32 + q*8);
      v8s bl = *(const v8s*)(W1l + (long)n*128 + s*32 + q*8);
      #pragma unroll
      for (int mt = 0; mt < 2; mt++) {
        v8s ah = *(const v8s*)&XH_(mt*16 + l15, s*32 + q*8);
        v8s al = *(const v8s*)&XL_(mt*16 + l15, s*32 + q*8);
        MFMA3(acc[mt], ah, al, bh, bl);
      }
    }
    float bb = b1[n];
    #pragma unroll
    for (int mt = 0; mt < 2; mt++)
      #pragma unroll
      for (int i = 0; i < 4; i++) {
        short h, l;
        split2(silu_f(acc[mt][i] + bb), h, l);
        TH_(mt*16 + q*4 + i, n) = h;
        TL_(mt*16 + q*4 + i, n) = l;
      }
  }
  __syncthreads();
  // GEMM2: phi = t2@Wm2 + b2 (384 cols; wave w -> n-tiles w*3..w*3+2)
  v4f acc[2][3] = {};
  #pragma unroll
  for (int s = 0; s < 4; s++) {
    v8s ah[2], al[2];
    #pragma unroll
    for (int mt = 0; mt < 2; mt++) {
      ah[mt] = *(const v8s*)&TH_(mt*16 + l15, s*32 + q*8);
      al[mt] = *(const v8s*)&TL_(mt*16 + l15, s*32 + q*8);
    }
    #pragma unroll
    for (int j = 0; j < 3; j++) {
      int n = (wv*3 + j)*16 + l15;
      v8s bh = *(const v8s*)(W2h + (long)n*128 + s*32 + q*8);
      v8s bl = *(const v8s*)(W2l + (long)n*128 + s*32 + q*8);
      #pragma unroll
      for (int mt = 0; mt < 2; mt++) { MFMA3(acc[mt][j], ah[mt], al[mt], bh, bl); }
    }
  }
  #pragma unroll
  for (int j = 0; j < 3; j++) {
    int n = (wv*3 + j)*16 + l15;
    int sl = n >> 7, col = n & 127;
    float* C = (sl == 0) ? C0 : (sl == 1) ? C1 : C2;
    float bb = b2[n];
    #pragma unroll
    for (int mt = 0; mt < 2; mt++)
      #pragma unroll
      for (int i = 0; i < 4; i++) {
        long row = r0 + mt*16 + q*4 + i;
        if (row < M) C[row*128 + col] = acc[mt][j][i] + bb;
      }
  }
  #undef XH_
  #undef XL_
  #undef TH_
  #undef TL_
}

// ---------------- FUSED message pass + Uv/Vv/Vn/s + a-MLP + update (muva, R23) ----------------
// R23 = R18 (verified best, 1332.7us) + fused output head on the last layer:
//  - last==1: skip dead x/v stores (~100MB), keep final x rows in LDS (XN), and compute
//    out = segsum(silu(x@Wo1+bo1)@Wo2+bo2) in-block (Wo1 is 32KB, L1-hot) with one
//    atomicAdd per node. Replaces out_kernel + its 25.6MB x re-read.
//  - sweep/pipeline identical to R18 (depth-2 zero-move, delta accumulation, wf pin,
//    base rows added in conversion phase).
__global__ void __launch_bounds__(512, 3) muva_kernel(
    const float* __restrict__ phi0, const float* __restrict__ phi1,
    const float* __restrict__ phi2, const float* __restrict__ vA,
    float* __restrict__ vB, float* __restrict__ x,
    const int* __restrict__ srcs, const float4* __restrict__ eg1,
    const float4* __restrict__ eg2, const int* __restrict__ indptr,
    const float* __restrict__ Wf_l, const float* __restrict__ bf_l,
    const short* __restrict__ Uth, const short* __restrict__ Utl,
    const short* __restrict__ Vth, const short* __restrict__ Vtl,
    const short* __restrict__ W1h, const short* __restrict__ W1l, const float* __restrict__ b1,
    const short* __restrict__ W2h, const short* __restrict__ W2l, const float* __restrict__ b2,
    const float* __restrict__ Wo1, const float* __restrict__ bo1,
    const float* __restrict__ Wo2, const float* __restrict__ bo2,
    const int* __restrict__ batch, float* __restrict__ out, int last) {
  __shared__ float smem[8896];   // 35584 B
  // region A floats [0,6720): VN [48][140] fp32 deltas during sweep,
  //   then converted IN PLACE to shorts: VNH[48][136] @0 | VNL[48][136] @6528
  //   then overlaid by CATH[16][264] @0 | CATL @4224 | T2H[16][136] @8448 | T2L @10624
  // region B floats [6720,8896): XN [16][136] fp32 (delta then full; intact until epilogue;
  //   on last layer holds FINAL x rows for the fused output head)
  short* sms = (short*)smem;
  #define VN(r,c)   smem[(r)*140 + (c)]
  #define XN(r,c)   smem[6720 + (r)*136 + (c)]
  #define VNH(r,c)  sms[(r)*136 + (c)]
  #define VNL(r,c)  sms[6528 + (r)*136 + (c)]
  #define CATH(r,c) sms[(r)*264 + (c)]
  #define CATL(r,c) sms[4224 + (r)*264 + (c)]
  #define T2H(r,c)  sms[8448 + (r)*136 + (c)]
  #define T2L(r,c)  sms[10624 + (r)*136 + (c)]
  const long NND = (long)NN*DD;
  int tid = threadIdx.x;
  long nb = (long)blockIdx.x * 16;
  // ---- phase E: edge sweep. 4 groups x 128 d-lanes; group g handles nodes 4g..4g+3 ----
  {
    int gs = __builtin_amdgcn_readfirstlane((int)(tid >> 7));   // wave-uniform group id
    int d  = tid & 127;
    float wf0[NB_], wf1[NB_], wf2[NB_];
    #pragma unroll
    for (int k = 0; k < NB_; k++) {
      wf0[k] = Wf_l[k*D3 + d];
      wf1[k] = Wf_l[k*D3 + DD + d];
      wf2[k] = Wf_l[k*D3 + 2*DD + d];
    }
    // pin: make each wf value an asm output -> not rematerializable (R18 behavior kept)
    #pragma unroll
    for (int k = 0; k < NB_; k++) {
      asm volatile("" : "+v"(wf0[k]), "+v"(wf1[k]), "+v"(wf2[k]));
    }
    float bf0 = bf_l[d], bf1 = bf_l[DD + d], bf2 = bf_l[2*DD + d];
    long n0g = nb + 4*gs;
    int b0  = __builtin_amdgcn_readfirstlane(indptr[n0g]);
    int b1_ = __builtin_amdgcn_readfirstlane(indptr[n0g+1]);
    int b2_ = __builtin_amdgcn_readfirstlane(indptr[n0g+2]);
    int b3_ = __builtin_amdgcn_readfirstlane(indptr[n0g+3]);
    int b4_ = __builtin_amdgcn_readfirstlane(indptr[n0g+4]);
    // pipeline state: slot A/B = {per-lane gathers, uniform geometry}; src ring 4 ahead
    int sA = 0, sB = 0;
    float p0A=0,p1A=0,p2A=0,w0A=0,w1A=0,w2A=0;
    float p0B=0,p1B=0,p2B=0,w0B=0,w1B=0,w2B=0;
    float4 g1A={}, g2A={}, g1B={}, g2B={};
    if (b0 < b4_) {
      int s0 = srcs[b0];
      long bb = (long)s0*DD + d;
      p0A = phi0[bb]; p1A = phi1[bb]; p2A = phi2[bb];
      w0A = vA[bb]; w1A = vA[NND+bb]; w2A = vA[2*NND+bb];
      g1A = eg1[b0]; g2A = eg2[b0];
    }
    if (b0 + 1 < b4_) {
      int s1v = srcs[b0+1];
      long bb = (long)s1v*DD + d;
      p0B = phi0[bb]; p1B = phi1[bb]; p2B = phi2[bb];
      w0B = vA[bb]; w1B = vA[NND+bb]; w2B = vA[2*NND+bb];
      g1B = eg1[b0+1]; g2B = eg2[b0+1];
    }
    if (b0 + 2 < b4_) sA = srcs[b0+2];
    if (b0 + 3 < b4_) sB = srcs[b0+3];
    float xacc=0.f, a0=0.f, a1=0.f, a2=0.f;
    int e = b0, cur = 0, nxt = b1_;
    // body: flush-check -> compute slot -> refill same slot for e+2 (no moves) -> src e+4
#define SW_BODY(P0,P1,P2,W0,W1,W2, G1, G2, SS) \
    { while (e >= nxt) { int nr = 4*gs + cur; \
        XN(nr, d) = xacc; VN(nr, d) = a0; VN(16+nr, d) = a1; VN(32+nr, d) = a2; \
        xacc = 0.f; a0 = 0.f; a1 = 0.f; a2 = 0.f; \
        cur++; nxt = (cur == 1) ? b2_ : (cur == 2) ? b3_ : b4_; } \
      float c2 = 2.0f * G1.y; \
      float rkm1 = 0.f, rk = G1.x, dot0 = 0.f, dot1 = 0.f, dot2 = 0.f; \
      _Pragma("unroll") \
      for (int k = 0; k < NB_; k++) { \
        dot0 = fmaf(rk, wf0[k], dot0); \
        dot1 = fmaf(rk, wf1[k], dot1); \
        dot2 = fmaf(rk, wf2[k], dot2); \
        float rn = fmaf(c2, rk, -rkm1); \
        rkm1 = rk; rk = rn; } \
      xacc = fmaf(P0, bf0*G1.z + G1.w*dot0, xacc); \
      float m1 = P1 * (bf1*G1.z + G1.w*dot1); \
      float m2 = P2 * (bf2*G1.z + G1.w*dot2); \
      a0 = fmaf(m1, G2.x, fmaf(m2, W0, a0)); \
      a1 = fmaf(m1, G2.y, fmaf(m2, W1, a1)); \
      a2 = fmaf(m1, G2.z, fmaf(m2, W2, a2)); \
      if (e + 2 < b4_) { \
        long bb = (long)SS*DD + d; \
        P0 = phi0[bb]; P1 = phi1[bb]; P2 = phi2[bb]; \
        W0 = vA[bb]; W1 = vA[NND+bb]; W2 = vA[2*NND+bb]; \
        G1 = eg1[e+2]; G2 = eg2[e+2]; } \
      if (e + 4 < b4_) SS = srcs[e+4]; \
      ++e; }
    while (e < b4_) {
      SW_BODY(p0A,p1A,p2A,w0A,w1A,w2A, g1A, g2A, sA)
      if (e >= b4_) break;
      SW_BODY(p0B,p1B,p2B,w0B,w1B,w2B, g1B, g2B, sB)
    }
#undef SW_BODY
    while (cur < 4) {
      int nr = 4*gs + cur;
      XN(nr, d) = xacc; VN(nr, d) = a0; VN(16+nr, d) = a1; VN(32+nr, d) = a2;
      xacc = 0.f; a0 = 0.f; a1 = 0.f; a2 = 0.f;
      cur++;
    }
  }
  // ---- issue base-row loads BEFORE the barrier (overlap with sweep stragglers) ----
  int lane = tid & 63, wv = tid >> 6;   // wv 0..7
  int l15 = lane & 15, q = lane >> 4;
  int dc = wv*16 + l15;                 // this wave's column slice
  float4 vb4[3]; float4 xb4;
  {
    int ch = tid * 3;                   // 1536 float4-chunks: 48 rows x 32
    #pragma unroll
    for (int j = 0; j < 3; j++) {
      int r = (ch + j) >> 5, c4 = (ch + j) & 31;
      vb4[j] = *(const float4*)(vA + (long)(r >> 4)*NND + (nb + (r & 15))*DD + c4*4);
    }
    int r = tid >> 5, c4 = tid & 31;
    xb4 = *(const float4*)(x + (nb + r)*DD + c4*4);
  }
  float vbold[4][3];
  #pragma unroll
  for (int i = 0; i < 4; i++)
    #pragma unroll
    for (int c = 0; c < 3; c++)
      vbold[i][c] = vA[(long)c*NND + (nb + q*4 + i)*DD + dc];
  __syncthreads();
  // ---- capture v delta, add bases to VN chunks (regs) and XN (in place) ----
  float voldd[4][3];
  #pragma unroll
  for (int i = 0; i < 4; i++)
    #pragma unroll
    for (int c = 0; c < 3; c++) voldd[i][c] = VN(c*16 + q*4 + i, dc);
  float4 cf[3];
  {
    int ch = tid * 3;
    #pragma unroll
    for (int j = 0; j < 3; j++) {
      int r = (ch + j) >> 5, c4 = (ch + j) & 31;
      float4 t = *(const float4*)&VN(r, c4*4);
      cf[j] = make_float4(vb4[j].x + t.x, vb4[j].y + t.y, vb4[j].z + t.z, vb4[j].w + t.w);
    }
    int r = tid >> 5, c4 = tid & 31;
    float4 t = *(float4*)&XN(r, c4*4);
    *(float4*)&XN(r, c4*4) = make_float4(xb4.x + t.x, xb4.y + t.y, xb4.z + t.z, xb4.w + t.w);
  }
  __syncthreads();                      // all fp32 reads done before short overwrite
  {
    int ch = tid * 3;
    #pragma unroll
    for (int j = 0; j < 3; j++) {
      int r = (ch + j) >> 5, c4 = (ch + j) & 31;
      split_store4(cf[j], &VNH(r, c4*4), &VNL(r, c4*4));
    }
  }
  __syncthreads();
  // ---- phase 1: U & V projections for column-slice dc (A-fragments pre-split) ----
  v4f aU[3] = {}, aV[3] = {};
  #pragma unroll
  for (int s = 0; s < 4; s++) {
    long boff = (long)dc*128 + s*32 + q*8;
    v8s buh = *(const v8s*)(Uth + boff);
    v8s bul = *(const v8s*)(Utl + boff);
    v8s bvh = *(const v8s*)(Vth + boff);
    v8s bvl = *(const v8s*)(Vtl + boff);
    #pragma unroll
    for (int c = 0; c < 3; c++) {
      v8s ah = *(const v8s*)&VNH(c*16 + l15, s*32 + q*8);
      v8s al = *(const v8s*)&VNL(c*16 + l15, s*32 + q*8);
      MFMA3(aU[c], ah, al, buh, bul);
      MFMA3(aV[c], ah, al, bvh, bvl);
    }
  }
  float sreg[4], vn2[4];
  #pragma unroll
  for (int i = 0; i < 4; i++) {
    sreg[i] = aU[0][i]*aV[0][i] + aU[1][i]*aV[1][i] + aU[2][i]*aV[2][i];
    vn2[i]  = aV[0][i]*aV[0][i] + aV[1][i]*aV[1][i] + aV[2][i]*aV[2][i];
  }
  __syncthreads();   // all reads of VNH/VNL complete before CAT overlay
  // ---- build cat = [x_new | Vn] directly as bf16 hi/lo (split once by producer) ----
  {
    int r = tid >> 5, c4 = tid & 31;   // 512 tasks: 16 rows x 32 float4-chunks
    float4 f = *(const float4*)&XN(r, c4*4);
    split_store4(f, &CATH(r, c4*4), &CATL(r, c4*4));
  }
  #pragma unroll
  for (int i = 0; i < 4; i++) {
    short h, l;
    split2(sqrtf(vn2[i] + 1e-8f), h, l);
    CATH(q*4 + i, 128 + dc) = h;
    CATL(q*4 + i, 128 + dc) = l;
  }
  __syncthreads();
  // ---- GEMM1: t2[:, dc] = silu(cat @ Wu1 + b1), K=256; t2 written pre-split ----
  {
    v4f acc = {};
    #pragma unroll
    for (int s = 0; s < 8; s++) {
      v8s ah = *(const v8s*)&CATH(l15, s*32 + q*8);
      v8s al = *(const v8s*)&CATL(l15, s*32 + q*8);
      v8s bh = *(const v8s*)(W1h + (long)dc*256 + s*32 + q*8);
      v8s bl = *(const v8s*)(W1l + (long)dc*256 + s*32 + q*8);
      MFMA3(acc, ah, al, bh, bl);
    }
    float bb = b1[dc];
    #pragma unroll
    for (int i = 0; i < 4; i++) {
      short h, l;
      split2(silu_f(acc[i] + bb), h, l);
      T2H(q*4 + i, dc) = h;
      T2L(q*4 + i, dc) = l;
    }
  }
  __syncthreads();
  // ---- GEMM2 + epilogue ----
  {
    v4f acc[3] = {};
    #pragma unroll
    for (int s = 0; s < 4; s++) {
      v8s ah = *(const v8s*)&T2H(l15, s*32 + q*8);
      v8s al = *(const v8s*)&T2L(l15, s*32 + q*8);
      #pragma unroll
      for (int g = 0; g < 3; g++) {
        int n = g*128 + dc;                 // avv: dc, asv: 128+dc, ass: 256+dc
        v8s bh = *(const v8s*)(W2h + (long)n*128 + s*32 + q*8);
        v8s bl = *(const v8s*)(W2l + (long)n*128 + s*32 + q*8);
        MFMA3(acc[g], ah, al, bh, bl);
      }
    }
    float bavv = b2[dc], basv = b2[128 + dc], bass = b2[256 + dc];
    #pragma unroll
    for (int i = 0; i < 4; i++) {
      int lr = q*4 + i;
      long row = nb + lr;
      float avv = acc[0][i] + bavv;
      float asv = acc[1][i] + basv;
      float ass = acc[2][i] + bass;
      float xf = XN(lr, dc) + ass + asv * sreg[i];
      if (!last) {
        x[row*DD + dc] = xf;
        #pragma unroll
        for (int c = 0; c < 3; c++)
          vB[(long)c*NND + row*DD + dc] = fmaf(avv, aU[c][i], voldd[i][c] + vbold[i][c]);
      } else {
        XN(lr, dc) = xf;    // keep final x row in LDS for the fused head
      }
    }
  }
  // ---- fused output head (last layer only): out += silu(x@Wo1+bo1)@Wo2 + bo2 ----
  if (last) {
    __syncthreads();        // all final XN writes visible
    int r = tid >> 5, hl = tid & 31;   // 16 rows x 32 lanes; lane handles h=hl and h=hl+32
    float a0 = bo1[hl], a1 = bo1[hl + 32];
    #pragma unroll 16
    for (int d2 = 0; d2 < DD; d2++) {
      float xv = XN(r, d2);
      a0 = fmaf(xv, Wo1[d2*HH + hl], a0);
      a1 = fmaf(xv, Wo1[d2*HH + hl + 32], a1);
    }
    float val = silu_f(a0) * Wo2[hl] + silu_f(a1) * Wo2[hl + 32];
    #pragma unroll
    for (int off = 16; off > 0; off >>= 1) val += __shfl_down(val, off, 32);
    if (hl == 0) atomicAdd(&out[batch[nb + r]], val + bo2[0]);
  }
  #undef VN
  #undef XN
  #undef VNH
  #undef VNL
  #undef CATH
  #undef CATL
  #undef T2H
  #undef T2L
}

// ---------------- launcher ----------------
extern "C" void kernel_launch(void* const* d_in, const int* in_sizes, int n_in,
                              void* d_out, int out_size, void* d_ws, size_t ws_size,
                              hipStream_t stream) {
  const int*   at_no = (const int*)d_in[0];
  const float* pos   = (const float*)d_in[1];
  const int*   ei    = (const int*)d_in[2];
  const int*   batch = (const int*)d_in[3];
  const float* emb   = (const float*)d_in[4];
  const float* Wf    = (const float*)d_in[5];
  const float* bfp   = (const float*)d_in[6];
  const float* Wm1   = (const float*)d_in[7];
  const float* bm1   = (const float*)d_in[8];
  const float* Wm2   = (const float*)d_in[9];
  const float* bm2   = (const float*)d_in[10];
  const float* U     = (const float*)d_in[11];
  const float* V     = (const float*)d_in[12];
  const float* Wu1   = (const float*)d_in[13];
  const float* bu1   = (const float*)d_in[14];
  const float* Wu2   = (const float*)d_in[15];
  const float* bu2   = (const float*)d_in[16];
  const float* Wo1   = (const float*)d_in[17];
  const float* bo1   = (const float*)d_in[18];
  const float* Wo2   = (const float*)d_in[19];
  const float* bo2   = (const float*)d_in[20];
  float* out = (float*)d_out;

  char* w = (char*)d_ws;
  auto alloc = [&](size_t bytes) -> void* {
    void* p = (void*)w;
    w += (bytes + 255) & ~(size_t)255;
    return p;
  };
  float*  x      = (float*)alloc(sizeof(float)*(size_t)NN*DD);
  float*  v_a    = (float*)alloc(sizeof(float)*(size_t)NN*D3);   // plane layout [3][NN][DD]
  float*  v_b    = (float*)alloc(sizeof(float)*(size_t)NN*D3);
  float*  t1     = (float*)alloc(sizeof(float)*(size_t)NN*DD);   // phi slice 2
  float*  phiS   = (float*)alloc(sizeof(float)*(size_t)NN*DD);   // phi slice 1
  float*  phi0   = (float*)alloc(sizeof(float)*(size_t)NN*DD);   // phi slice 0
  short*  wbh    = (short*)alloc(sizeof(short)*(size_t)3*LSZ);   // bf16-hi weights
  short*  wbl    = (short*)alloc(sizeof(short)*(size_t)3*LSZ);   // bf16-lo weights
  int*    srcs   = (int*)alloc(sizeof(int)*(size_t)ECAP);
  float4* eg1    = (float4*)alloc(sizeof(float4)*(size_t)ECAP);
  float4* eg2    = (float4*)alloc(sizeof(float4)*(size_t)ECAP);
  int*    indptr = (int*)alloc(sizeof(int)*((size_t)NN+1));
  int*    counts = (int*)alloc(sizeof(int)*(size_t)NN);

  if ((size_t)(w - (char*)d_ws) > ws_size) {   // diagnostic guard: zeros => ws too small
    zero_f_kernel<<<2, 256, 0, stream>>>(out, NG_);
    return;
  }

  zero_f_kernel<<<2048, 256, 0, stream>>>(v_a, (long)NN*D3);
  zero_f_kernel<<<2, 256, 0, stream>>>(out, NG_);
  zero_i_kernel<<<64, 256, 0, stream>>>(counts, NN);
  init_x_kernel<<<(NN*DD + 255)/256, 256, 0, stream>>>(at_no, emb, x);
  prep_w_kernel<<<(3*LSZ + 255)/256, 256, 0, stream>>>(Wm1, Wm2, U, V, Wu1, Wu2, wbh, wbl);
  hist_kernel<<<(NE + 255)/256, 256, 0, stream>>>(ei, pos, counts);
  scan_kernel<<<1, 1024, 0, stream>>>(counts, indptr, NN);
  zero_i_kernel<<<64, 256, 0, stream>>>(counts, NN);
  fill_kernel<<<(NE + 255)/256, 256, 0, stream>>>(ei, pos, indptr, counts, srcs, eg1, eg2);

  const int MB = (NN + 31) / 32;    // 1563
  float* vcur = v_a;
  float* vnext = v_b;
  for (int l = 0; l < 3; l++) {
    const float* Wf_l  = Wf  + (size_t)l*NB_*D3;
    const float* bf_l  = bfp + (size_t)l*D3;
    const float* bm1_l = bm1 + (size_t)l*DD;
    const float* bm2_l = bm2 + (size_t)l*D3;
    const float* bu1_l = bu1 + (size_t)l*DD;
    const float* bu2_l = bu2 + (size_t)l*D3;
    const short* Lh = wbh + (size_t)l*LSZ;
    const short* Ll = wbl + (size_t)l*LSZ;
    const short* Wm1h = Lh,          *Wm1L = Ll;
    const short* Wm2h = Lh + 16384,  *Wm2L = Ll + 16384;
    const short* Uh   = Lh + 65536,  *UL   = Ll + 65536;
    const short* Vh   = Lh + 81920,  *VL   = Ll + 81920;
    const short* Wu1h = Lh + 98304,  *Wu1L = Ll + 98304;
    const short* Wu2h = Lh + 131072, *Wu2L = Ll + 131072;

    // fused node-MLP: x -> t2 (LDS) -> phi slices {phi0, phiS, t1}
    mlp_phi_kernel<<<MB, 512, 0, stream>>>(x, Wm1h, Wm1L, bm1_l, Wm2h, Wm2L, bm2_l,
                                           phi0, phiS, t1, NN);
    // fused: edge sweep + U/V proj + a-MLP + x,v update; last layer also computes the
    // output head in-block (x_new/v_new stay in LDS; dead stores skipped)
    muva_kernel<<<NN/16, 512, 0, stream>>>(phi0, phiS, t1, vcur, vnext, x,
                                           srcs, eg1, eg2, indptr, Wf_l, bf_l,
                                           Uh, UL, Vh, VL,
                                           Wu1h, Wu1L, bu1_l, Wu2h, Wu2L, bu2_l,
                                           Wo1, bo1, Wo2, bo2, batch, out,
                                           (l == 2) ? 1 : 0);

    float* tmp = vcur; vcur = vnext; vnext = tmp;
  }

  (void)in_sizes; (void)n_in; (void)out_size; (void)ws_size;
}